// Round 8
// baseline (332.577 us; speedup 1.0000x reference)
//
#include <hip/hip_runtime.h>
#include <hip/hip_cooperative_groups.h>
#include <cstdint>
#include <cstddef>

namespace cg = cooperative_groups;

typedef unsigned int u32;
typedef unsigned long long u64;

#define NTOT 122740      // total proposals (records) per batch
#define NPAIR 61370
#define KTOP 1024        // top-K kept per batch (deterministic bin-cutoff set)
#define WIN  256         // IoU-matrix window over the sorted list
#define NBIN 4096
#define SCORE_T 0.25f
#define TBITS 0x3E800000u       // bit pattern of 0.25f
#define HSPLIT_BITS 0x3EFFF000u // bits >= this  <=>  score_bin >= 2048
#define CSTRIDE 64              // counter padding (u32s); [0]=nH [1]=nL
#define CAP_H 40960
#define CAP_L 20480

#define NBLK 256                // cooperative grid: 1 block per CU
#define SLICES 8                // decode slices per batch (NBLK/32)
#define SLICE_REC 15360         // records per slice (multiple of 1024; 8*15360 >= NTOT)
#define CHUNK 1024              // records per staged chunk

// concatenated float4 layout per batch (all level boundaries are f4-aligned):
//   L2: f4 [0,      138624)  p2, batch stride 138624 f4
//   L3: f4 [138624, 173280)  p3, stride 34656
//   L4: f4 [173280, 181944)  p4, stride 8664
//   L5: f4 [181944, 184110)  p5, stride 2166
#define F4TOT 184110
#define F4B3 138624
#define F4B4 173280
#define F4B5 181944

// ws layout (bytes):
//   counters: 32*64*4    = 8192      @ 0
//   candH:    32*CAP_H*8 = 10485760  @ 8192
//   candL:    32*CAP_L*8 = 5242880   @ 10493952   (end ~15.0 MB)
#define WS_CANDH 8192
#define WS_CANDL 10493952

// ---------------------------------------------------------------- helpers
__device__ __forceinline__ float sigm(float x) { return 1.0f / (1.0f + expf(-x)); }

__device__ __forceinline__ int score_bin(u32 bits) {
  return min(4095, 1 + (int)((bits - TBITS) >> 12));
}

__device__ __forceinline__ u64 shfl_u64(u64 x, int src) {
  int lo = __shfl((int)(u32)x, src, 64);
  int hi = __shfl((int)(u32)(x >> 32), src, 64);
  return ((u64)(u32)hi << 32) | (u32)lo;
}

// fallback-only: scores for record pair P (records 2P, 2P+1) of batch b
__device__ __forceinline__ void score_pair(int P, int b,
    const float* __restrict__ p2, const float* __restrict__ p3,
    const float* __restrict__ p4, const float* __restrict__ p5,
    u32& b0, u32& b1, u32& gi0, u32& gi1)
{
  int t0 = 2 * P;
  const float* p; int l0, LN;
  if (t0 < 92416)       { p = p2; l0 = t0;          LN = 92416; }
  else if (t0 < 115520) { p = p3; l0 = t0 - 92416;  LN = 23104; }
  else if (t0 < 121296) { p = p4; l0 = t0 - 115520; LN = 5776;  }
  else                  { p = p5; l0 = t0 - 121296; LN = 1444;  }
  const float* q = p + ((size_t)b * LN + (size_t)l0) * 6;
  float4 v1 = *(const float4*)(q + 4);
  float4 v2 = *(const float4*)(q + 8);
  float s0 = sigm(v1.x) * sigm(v1.y);
  float s1 = sigm(v2.z) * sigm(v2.w);
  b0 = (s0 >= SCORE_T) ? __float_as_uint(s0) : 0u;
  b1 = (s1 >= SCORE_T) ? __float_as_uint(s1) : 0u;
  gi0 = (u32)t0; gi1 = (u32)(t0 + 1);
}

__device__ float4 decode_box_from_gidx(u32 gidx, int b,
    const float* __restrict__ p2, const float* __restrict__ p3,
    const float* __restrict__ p4, const float* __restrict__ p5)
{
  const float* p; int t, H, W; float stride;
  float aw0, ah0, aw1, ah1, aw2, ah2, aw3, ah3;
  if (gidx < 92416u) {
    p = p2 + (size_t)b * 92416 * 6; t = (int)gidx; H = 152; W = 152; stride = 4.0f;
    aw0=12.f; ah0=16.f; aw1=19.f; ah1=36.f; aw2=40.f; ah2=28.f; aw3=36.f; ah3=75.f;
  } else if (gidx < 115520u) {
    p = p3 + (size_t)b * 23104 * 6; t = (int)(gidx - 92416u); H = 76; W = 76; stride = 8.0f;
    aw0=36.f; ah0=75.f; aw1=76.f; ah1=55.f; aw2=72.f; ah2=146.f; aw3=142.f; ah3=110.f;
  } else if (gidx < 121296u) {
    p = p4 + (size_t)b * 5776 * 6; t = (int)(gidx - 115520u); H = 38; W = 38; stride = 16.0f;
    aw0=72.f; ah0=146.f; aw1=142.f; ah1=110.f; aw2=192.f; ah2=243.f; aw3=459.f; ah3=401.f;
  } else {
    p = p5 + (size_t)b * 1444 * 6; t = (int)(gidx - 121296u); H = 19; W = 19; stride = 32.0f;
    aw0=142.f; ah0=110.f; aw1=192.f; ah1=243.f; aw2=300.f; ah2=300.f; aw3=459.f; ah3=401.f;
  }
  int HW = H * W;
  int a = t / HW;
  int r = t - a * HW;
  int y = r / W;
  int x = r - y * W;
  const float* q = p + (size_t)t * 6;
  float2 t01 = *(const float2*)(q + 0);
  float2 t23 = *(const float2*)(q + 2);
  float cx = (sigm(t01.x) + (float)x) * stride;
  float cy = (sigm(t01.y) + (float)y) * stride;
  float aw = (a == 0) ? aw0 : (a == 1) ? aw1 : (a == 2) ? aw2 : aw3;
  float ah = (a == 0) ? ah0 : (a == 1) ? ah1 : (a == 2) ? ah2 : ah3;
  float bw = expf(t23.x) * aw;
  float bh = expf(t23.y) * ah;
  return make_float4(cx - 0.5f * bw, cy - 0.5f * bh, cx + 0.5f * bw, cy + 0.5f * bh);
}

__device__ __forceinline__ bool iou_gt(float4 A, float4 B) {
  float ltx = fmaxf(A.x, B.x), lty = fmaxf(A.y, B.y);
  float rbx = fminf(A.z, B.z), rby = fminf(A.w, B.w);
  float w = fmaxf(rbx - ltx, 0.0f), h = fmaxf(rby - lty, 0.0f);
  float inter = w * h;
  float a1 = fmaxf(A.z - A.x, 0.0f) * fmaxf(A.w - A.y, 0.0f);
  float a2 = fmaxf(B.z - B.x, 0.0f) * fmaxf(B.w - B.y, 0.0f);
  float iou = inter / (a1 + a2 - inter + 1e-9f);
  return iou > 0.5f;
}

// ---------------------------------------------------------------- fused cooperative kernel
// 256 blocks x 1024 thr, 1 block/CU. Phases:
//   0: zero counters; grid.sync
//   1: decode (8 slices/batch, dense f4 LDS staging, append H/L); grid.sync
//   2: blocks 0..31: hist+scan+scatter+rank-sort+IoU+greedy NMS (all in LDS)
__global__ __launch_bounds__(1024, 1)
void fused_kernel(const float* __restrict__ p2, const float* __restrict__ p3,
                  const float* __restrict__ p4, const float* __restrict__ p5,
                  u32* __restrict__ counters,
                  uint2* __restrict__ candH, uint2* __restrict__ candL,
                  float* __restrict__ out)
{
  cg::grid_group grid = cg::this_grid();
  const int tid = threadIdx.x;
  const int bid = blockIdx.x;

  // ---- decode-phase LDS
  __shared__ float4 sbuf4[1536];          // 24 KB  staged chunk (1024 records)
  __shared__ uint2 stH[CHUNK];            // 8 KB
  __shared__ uint2 stL[CHUNK];            // 8 KB
  __shared__ u32 s_cH, s_cL, s_bH, s_bL;
  // ---- backend LDS
  __shared__ u32 sstart[NBIN];            // 16 KB
  __shared__ u32 scur[NBIN];              // 16 KB
  __shared__ u64 skey[KTOP];              // 8 KB
  __shared__ u64 skey2[KTOP];             // 8 KB
  __shared__ float4 sbox[WIN];            // 4 KB
  __shared__ u64 smat[WIN * 4];           // 8 KB
  __shared__ float4 selbox[100];          // 1.6 KB
  __shared__ int s_misc[4];
  __shared__ int s_B, s_n;

  // ================= phase 0: zero counters =================
  if (bid < 32 && tid < CSTRIDE) counters[(size_t)bid * CSTRIDE + tid] = 0u;
  grid.sync();

  // ================= phase 1: decode =================
  {
    const int b = bid >> 3;               // batch
    const int s = bid & 7;                // slice
    const int SS = s * SLICE_REC;
    const int SE = min(SS + SLICE_REC, NTOT);
    u32* gcH = counters + (size_t)b * CSTRIDE;
    u32* gcL = gcH + 1;
    uint2* gH = candH + (size_t)b * CAP_H;
    uint2* gL = candL + (size_t)b * CAP_L;
    const float4* q2 = (const float4*)p2;
    const float4* q3 = (const float4*)p3;
    const float4* q4 = (const float4*)p4;
    const float4* q5 = (const float4*)p5;

    for (int CB = SS; CB < SE; CB += CHUNK) {
      if (tid == 0) { s_cH = 0u; s_cL = 0u; }
      // stage: f4 range [FS, FE)
      const int FS = (CB >> 1) * 3;       // CB*6/4, CB multiple of 1024
      const int FE = min(FS + 1536, F4TOT);
      const int nf = FE - FS;
      if (tid < nf) {                      // nf <= 1536; threads 0..1023 + loop tail
        int idx4 = FS + tid;
        const float4* src;
        if (idx4 < F4B3)      src = q2 + (size_t)b * 138624 + idx4;
        else if (idx4 < F4B4) src = q3 + (size_t)b * 34656  + (idx4 - F4B3);
        else if (idx4 < F4B5) src = q4 + (size_t)b * 8664   + (idx4 - F4B4);
        else                  src = q5 + (size_t)b * 2166   + (idx4 - F4B5);
        sbuf4[tid] = *src;
      }
      {
        int i2 = tid + 1024;
        if (i2 < nf) {
          int idx4 = FS + i2;
          const float4* src;
          if (idx4 < F4B3)      src = q2 + (size_t)b * 138624 + idx4;
          else if (idx4 < F4B4) src = q3 + (size_t)b * 34656  + (idx4 - F4B3);
          else if (idx4 < F4B5) src = q4 + (size_t)b * 8664   + (idx4 - F4B4);
          else                  src = q5 + (size_t)b * 2166   + (idx4 - F4B5);
          sbuf4[i2] = *src;
        }
      }
      __syncthreads();
      // consume: record rg = CB + tid
      {
        int rg = CB + tid;
        if (rg < SE) {
          const float* sbuf = (const float*)sbuf4;
          float2 cc = *(const float2*)&sbuf[tid * 6 + 4];
          float sc = sigm(cc.x) * sigm(cc.y);
          if (sc >= SCORE_T) {
            u32 bits = __float_as_uint(sc);
            bool H = (bits >= HSPLIT_BITS);
            u32 pos = atomicAdd(H ? &s_cH : &s_cL, 1u);
            (H ? stH : stL)[pos] = make_uint2(bits, (u32)rg);
          }
        }
      }
      __syncthreads();
      if (tid == 0) {
        s_bH = s_cH ? atomicAdd(gcH, s_cH) : 0u;
        s_bL = s_cL ? atomicAdd(gcL, s_cL) : 0u;
      }
      __syncthreads();
      {
        const u32 mH = s_cH, mL = s_cL, bH = s_bH, bL = s_bL;
        for (u32 i = tid; i < mH; i += 1024) { u32 d = bH + i; if (d < (u32)CAP_H) gH[d] = stH[i]; }
        for (u32 i = tid; i < mL; i += 1024) { u32 d = bL + i; if (d < (u32)CAP_L) gL[d] = stL[i]; }
      }
      __syncthreads();
    }
  }
  __threadfence();
  grid.sync();

  // ================= phase 2: backend (blocks 0..31) =================
  if (bid >= 32) return;
  const int b = bid;

  const u32 nHc = counters[(size_t)b * CSTRIDE];
  const u32 nLc = counters[(size_t)b * CSTRIDE + 1];
  const bool readL = (nHc < (u32)KTOP);
  const bool fb = (nHc > (u32)CAP_H) || (readL && nLc > (u32)CAP_L);

  for (int i = tid; i < NBIN; i += 1024) scur[i] = 0u;
  __syncthreads();

  // ---- hist
  if (!fb) {
    const uint2* gH = candH + (size_t)b * CAP_H;
    for (u32 i = tid; i < nHc; i += 1024) atomicAdd(&scur[score_bin(gH[i].x)], 1u);
    if (readL) {
      const uint2* gL = candL + (size_t)b * CAP_L;
      for (u32 i = tid; i < nLc; i += 1024) atomicAdd(&scur[score_bin(gL[i].x)], 1u);
    }
  } else {
    for (int P = tid; P < NPAIR; P += 1024) {
      u32 b0, b1, gi0, gi1;
      score_pair(P, b, p2, p3, p4, p5, b0, b1, gi0, gi1);
      if (b0) atomicAdd(&scur[score_bin(b0)], 1u);
      if (b1) atomicAdd(&scur[score_bin(b1)], 1u);
    }
  }
  __syncthreads();

  // ---- wave-0 shfl suffix scan + min-reduce cutoff
  if (tid < 64) {
    u32 h[64];
    #pragma unroll
    for (int k = 0; k < 64; ++k) h[k] = scur[tid * 64 + k];
    u32 lsum = 0;
    #pragma unroll
    for (int k = 0; k < 64; ++k) lsum += h[k];
    u32 S = lsum;
    #pragma unroll
    for (int off = 1; off < 64; off <<= 1) {
      u32 v = (u32)__shfl_down((int)S, off, 64);
      if (tid + off < 64) S += v;
    }
    u32 c = S - lsum;                           // cnt_ge(64*tid + 64)
    int Bv = -1; u32 nv = 0;
    for (int k = 63; k >= 0; --k) {
      sstart[tid * 64 + k] = c;                 // cnt_ge(bin+1)
      c += h[k];                                // cnt_ge(bin)
      if (c <= (u32)KTOP) { Bv = tid * 64 + k; nv = c; }
    }
    u32 pk = (Bv < 0) ? 0xFFFFFFFFu : (((u32)Bv << 12) | nv);
    #pragma unroll
    for (int off = 32; off >= 1; off >>= 1) {
      u32 o = (u32)__shfl_down((int)pk, off, 64);
      if (tid + off < 64) pk = min(pk, o);
    }
    if (tid == 0) {
      if (pk == 0xFFFFFFFFu) { s_B = 4095; s_n = KTOP; }
      else { s_B = max((int)(pk >> 12), 1); s_n = (int)(pk & 0xFFFu); }
    }
  }
  __syncthreads();
  const int B = s_B;
  const int n = min(s_n, KTOP);

  for (int i = tid; i < NBIN; i += 1024) scur[i] = sstart[i];
  __syncthreads();

  // ---- scatter survivors into counting slots
  if (!fb) {
    const uint2* gH = candH + (size_t)b * CAP_H;
    for (u32 i = tid; i < nHc; i += 1024) {
      uint2 e = gH[i];
      int bin = score_bin(e.x);
      if (bin >= B) {
        u32 slot = atomicAdd(&scur[bin], 1u);
        if (slot < (u32)KTOP) skey[slot] = ((u64)e.x << 32) | (u32)(~e.y);
      }
    }
    if (readL) {
      const uint2* gL = candL + (size_t)b * CAP_L;
      for (u32 i = tid; i < nLc; i += 1024) {
        uint2 e = gL[i];
        int bin = score_bin(e.x);
        if (bin >= B) {
          u32 slot = atomicAdd(&scur[bin], 1u);
          if (slot < (u32)KTOP) skey[slot] = ((u64)e.x << 32) | (u32)(~e.y);
        }
      }
    }
  } else {
    for (int P = tid; P < NPAIR; P += 1024) {
      u32 b0, b1, gi0, gi1;
      score_pair(P, b, p2, p3, p4, p5, b0, b1, gi0, gi1);
      if (b0) { int bin = score_bin(b0);
        if (bin >= B) { u32 slot = atomicAdd(&scur[bin], 1u);
          if (slot < (u32)KTOP) skey[slot] = ((u64)b0 << 32) | (u32)(~gi0); } }
      if (b1) { int bin = score_bin(b1);
        if (bin >= B) { u32 slot = atomicAdd(&scur[bin], 1u);
          if (slot < (u32)KTOP) skey[slot] = ((u64)b1 << 32) | (u32)(~gi1); } }
    }
  }
  __syncthreads();

  // ---- exact rank sort within bins (barrier-free)
  for (int s = tid; s < n; s += 1024) {
    u64 k = skey[s];
    int bin = score_bin((u32)(k >> 32));
    int st = (int)sstart[bin];
    int en = (int)scur[bin];
    u32 r = 0;
    for (int j = st; j < en; ++j) r += (skey[j] > k) ? 1u : 0u;
    skey2[st + r] = k;
  }
  __syncthreads();

  const int Wn = min(n, WIN);

  // ---- window boxes
  if (tid < WIN) {
    sbox[tid] = (tid < Wn) ? decode_box_from_gidx(~(u32)skey2[tid], b, p2, p3, p4, p5)
                           : make_float4(0.f, 0.f, 0.f, 0.f);
  }
  __syncthreads();

  // ---- IoU bitmask matrix; row = tid&255, word = tid>>8 (broadcast reads)
  {
    int row = tid & 255, word = tid >> 8;
    u64 bits = 0;
    if (row < Wn) {
      float4 A = sbox[row];
      int j0 = word * 64;
      int je = min(64, Wn - j0);
      for (int j = 0; j < je; ++j)
        if (iou_gt(A, sbox[j0 + j])) bits |= (1ull << j);
    }
    smat[word * 256 + row] = bits;
  }
  __syncthreads();

  // ---- greedy selection on wave 0, matrix rows in registers
  if (tid < 64) {
    const int lane = tid;
    u64 m0[4], m1[4], m2[4], m3[4];
    #pragma unroll
    for (int w = 0; w < 4; ++w) {
      m0[w] = smat[w * 256 +   0 + lane];
      m1[w] = smat[w * 256 +  64 + lane];
      m2[w] = smat[w * 256 + 128 + lane];
      m3[w] = smat[w * 256 + 192 + lane];
    }
    u64 live[4];
    #pragma unroll
    for (int g2 = 0; g2 < 4; ++g2) {
      int lo = g2 * 64;
      live[g2] = (Wn >= lo + 64) ? ~0ull : (Wn > lo ? ((1ull << (Wn - lo)) - 1ull) : 0ull);
    }
    int sel = 0;
    #pragma unroll 1
    for (int w2 = 0; w2 < 4; ++w2) {
      while (live[w2] && sel < 100) {
        int j = (int)__ffsll(live[w2]) - 1;
        int p = (w2 << 6) + j;
        u64 r0, r1, r2, r3;
        if (w2 == 0)      { r0 = shfl_u64(m0[0], j); r1 = shfl_u64(m0[1], j); r2 = shfl_u64(m0[2], j); r3 = shfl_u64(m0[3], j); }
        else if (w2 == 1) { r0 = shfl_u64(m1[0], j); r1 = shfl_u64(m1[1], j); r2 = shfl_u64(m1[2], j); r3 = shfl_u64(m1[3], j); }
        else if (w2 == 2) { r0 = shfl_u64(m2[0], j); r1 = shfl_u64(m2[1], j); r2 = shfl_u64(m2[2], j); r3 = shfl_u64(m2[3], j); }
        else              { r0 = shfl_u64(m3[0], j); r1 = shfl_u64(m3[1], j); r2 = shfl_u64(m3[2], j); r3 = shfl_u64(m3[3], j); }
        live[0] &= ~r0; live[1] &= ~r1; live[2] &= ~r2; live[3] &= ~r3;
        live[w2] &= ~(1ull << j);
        if (lane == 0) {
          float4 box = sbox[p];
          u64 k = skey2[p];
          float sc = __uint_as_float((u32)(k >> 32));
          selbox[sel] = box;
          float* orow = out + (size_t)b * 500 + (size_t)sel * 5;
          orow[0] = box.x; orow[1] = box.y; orow[2] = box.z; orow[3] = box.w; orow[4] = sc;
        }
        sel++;
      }
    }
    if (lane == 0) {
      s_misc[2] = sel;
      s_misc[3] = (sel < 100 && n > WIN) ? 1 : 0;
    }
  }
  __syncthreads();

  // ---- exact slow path beyond the window (statistically never taken)
  if (s_misc[3]) {
    if (tid < 64) {
      const int lane = tid;
      int sel = s_misc[2];
      for (int p = WIN; p < n && sel < 100; ++p) {
        u64 k = skey2[p];
        float4 box = decode_box_from_gidx(~(u32)k, b, p2, p3, p4, p5);
        bool hit = false;
        if (lane < sel) hit = iou_gt(selbox[lane], box);
        if (lane + 64 < sel) hit = hit || iou_gt(selbox[lane + 64], box);
        u64 anyhit = __ballot(hit);
        if (anyhit == 0ull) {
          if (lane == 0) {
            selbox[sel] = box;
            float sc = __uint_as_float((u32)(k >> 32));
            float* orow = out + (size_t)b * 500 + (size_t)sel * 5;
            orow[0] = box.x; orow[1] = box.y; orow[2] = box.z; orow[3] = box.w; orow[4] = sc;
          }
          sel++;
        }
      }
      if (lane == 0) s_misc[2] = sel;
    }
  }
  __syncthreads();

  // ---- zero-fill remaining rows
  const int nsel = s_misc[2];
  for (int i = tid; i < (100 - nsel) * 5; i += 1024)
    out[(size_t)b * 500 + (size_t)nsel * 5 + i] = 0.0f;
}

// ---------------------------------------------------------------- launch
extern "C" void kernel_launch(void* const* d_in, const int* in_sizes, int n_in,
                              void* d_out, int out_size, void* d_ws, size_t ws_size,
                              hipStream_t stream) {
  const float* p2 = (const float*)d_in[0];
  const float* p3 = (const float*)d_in[1];
  const float* p4 = (const float*)d_in[2];
  const float* p5 = (const float*)d_in[3];
  float* out = (float*)d_out;

  unsigned char* w = (unsigned char*)d_ws;
  u32*   counters = (u32*)w;
  uint2* candH    = (uint2*)(w + WS_CANDH);
  uint2* candL    = (uint2*)(w + WS_CANDL);

  void* args[] = { (void*)&p2, (void*)&p3, (void*)&p4, (void*)&p5,
                   (void*)&counters, (void*)&candH, (void*)&candL, (void*)&out };
  hipLaunchCooperativeKernel((const void*)fused_kernel, dim3(NBLK), dim3(1024),
                             args, 0, stream);
}

// Round 9
// 176.180 us; speedup vs baseline: 1.8877x; 1.8877x over previous
//
#include <hip/hip_runtime.h>
#include <cstdint>
#include <cstddef>

typedef unsigned int u32;
typedef unsigned long long u64;

#define NTOT 122740      // total proposals (records) per batch
#define NPAIR 61370
#define KTOP 1024        // top-K kept per batch (deterministic bin-cutoff set)
#define WIN  256         // IoU-matrix window over the sorted list
#define NBIN 4096
#define SCORE_T 0.25f
#define TBITS 0x3E800000u       // bit pattern of 0.25f

// range thresholds on score bits (bin boundaries 3584/3072/2560/2048)
#define RT0 0x3F5DF000u   // bin >= 3584
#define RT1 0x3F3FF000u   // bin >= 3072
#define RT2 0x3F1FF000u   // bin >= 2560
#define RT3 0x3EFFF000u   // bin >= 2048

#define CSTRIDE 128             // counters per batch (u32); counter r at r*16 (64B apart)
// per-batch range capacities and offsets (entries)
#define CAP0 4096
#define CAP1 8192
#define CAP2 12288
#define CAP3 16384
#define CAP4 16384
#define OFF0 0
#define OFF1 4096
#define OFF2 12288
#define OFF3 24576
#define OFF4 40960
#define BATCH_ENT 57344

// concatenated float4 layout per batch (all level boundaries are f4-aligned):
//   L2: f4 [0,      138624)  p2, batch stride 138624 f4
//   L3: f4 [138624, 173280)  p3, stride 34656
//   L4: f4 [173280, 181944)  p4, stride 8664
//   L5: f4 [181944, 184110)  p5, stride 2166
#define F4TOT 184110
#define F4B3 138624
#define F4B4 173280
#define F4B5 181944

// ws layout (bytes):
//   counters: 32*128*4        = 16384     @ 0
//   cand:     32*57344*8      = 14680064  @ 16384   (~14.7 MB total)
#define WS_CAND 16384

// ---------------------------------------------------------------- helpers
__device__ __forceinline__ float sigm(float x) { return 1.0f / (1.0f + expf(-x)); }

__device__ __forceinline__ int score_bin(u32 bits) {
  return min(4095, 1 + (int)((bits - TBITS) >> 12));
}

__device__ __forceinline__ u64 shfl_u64(u64 x, int src) {
  int lo = __shfl((int)(u32)x, src, 64);
  int hi = __shfl((int)(u32)(x >> 32), src, 64);
  return ((u64)(u32)hi << 32) | (u32)lo;
}

// fallback-only: scores for record pair P (records 2P, 2P+1) of batch b
__device__ __forceinline__ void score_pair(int P, int b,
    const float* __restrict__ p2, const float* __restrict__ p3,
    const float* __restrict__ p4, const float* __restrict__ p5,
    u32& b0, u32& b1, u32& gi0, u32& gi1)
{
  int t0 = 2 * P;
  const float* p; int l0, LN;
  if (t0 < 92416)       { p = p2; l0 = t0;          LN = 92416; }
  else if (t0 < 115520) { p = p3; l0 = t0 - 92416;  LN = 23104; }
  else if (t0 < 121296) { p = p4; l0 = t0 - 115520; LN = 5776;  }
  else                  { p = p5; l0 = t0 - 121296; LN = 1444;  }
  const float* q = p + ((size_t)b * LN + (size_t)l0) * 6;
  float4 v1 = *(const float4*)(q + 4);
  float4 v2 = *(const float4*)(q + 8);
  float s0 = sigm(v1.x) * sigm(v1.y);
  float s1 = sigm(v2.z) * sigm(v2.w);
  b0 = (s0 >= SCORE_T) ? __float_as_uint(s0) : 0u;
  b1 = (s1 >= SCORE_T) ? __float_as_uint(s1) : 0u;
  gi0 = (u32)t0; gi1 = (u32)(t0 + 1);
}

__device__ float4 decode_box_from_gidx(u32 gidx, int b,
    const float* __restrict__ p2, const float* __restrict__ p3,
    const float* __restrict__ p4, const float* __restrict__ p5)
{
  const float* p; int t, H, W; float stride;
  float aw0, ah0, aw1, ah1, aw2, ah2, aw3, ah3;
  if (gidx < 92416u) {
    p = p2 + (size_t)b * 92416 * 6; t = (int)gidx; H = 152; W = 152; stride = 4.0f;
    aw0=12.f; ah0=16.f; aw1=19.f; ah1=36.f; aw2=40.f; ah2=28.f; aw3=36.f; ah3=75.f;
  } else if (gidx < 115520u) {
    p = p3 + (size_t)b * 23104 * 6; t = (int)(gidx - 92416u); H = 76; W = 76; stride = 8.0f;
    aw0=36.f; ah0=75.f; aw1=76.f; ah1=55.f; aw2=72.f; ah2=146.f; aw3=142.f; ah3=110.f;
  } else if (gidx < 121296u) {
    p = p4 + (size_t)b * 5776 * 6; t = (int)(gidx - 115520u); H = 38; W = 38; stride = 16.0f;
    aw0=72.f; ah0=146.f; aw1=142.f; ah1=110.f; aw2=192.f; ah2=243.f; aw3=459.f; ah3=401.f;
  } else {
    p = p5 + (size_t)b * 1444 * 6; t = (int)(gidx - 121296u); H = 19; W = 19; stride = 32.0f;
    aw0=142.f; ah0=110.f; aw1=192.f; ah1=243.f; aw2=300.f; ah2=300.f; aw3=459.f; ah3=401.f;
  }
  int HW = H * W;
  int a = t / HW;
  int r = t - a * HW;
  int y = r / W;
  int x = r - y * W;
  const float* q = p + (size_t)t * 6;
  float2 t01 = *(const float2*)(q + 0);
  float2 t23 = *(const float2*)(q + 2);
  float cx = (sigm(t01.x) + (float)x) * stride;
  float cy = (sigm(t01.y) + (float)y) * stride;
  float aw = (a == 0) ? aw0 : (a == 1) ? aw1 : (a == 2) ? aw2 : aw3;
  float ah = (a == 0) ? ah0 : (a == 1) ? ah1 : (a == 2) ? ah2 : ah3;
  float bw = expf(t23.x) * aw;
  float bh = expf(t23.y) * ah;
  return make_float4(cx - 0.5f * bw, cy - 0.5f * bh, cx + 0.5f * bw, cy + 0.5f * bh);
}

__device__ __forceinline__ bool iou_gt(float4 A, float4 B) {
  float ltx = fmaxf(A.x, B.x), lty = fmaxf(A.y, B.y);
  float rbx = fminf(A.z, B.z), rby = fminf(A.w, B.w);
  float w = fmaxf(rbx - ltx, 0.0f), h = fmaxf(rby - lty, 0.0f);
  float inter = w * h;
  float a1 = fmaxf(A.z - A.x, 0.0f) * fmaxf(A.w - A.y, 0.0f);
  float a2 = fmaxf(B.z - B.x, 0.0f) * fmaxf(B.w - B.y, 0.0f);
  float iou = inter / (a1 + a2 - inter + 1e-9f);
  return iou > 0.5f;
}

// ---------------------------------------------------------------- A: decode + 5-range classify
// grid (120, 32), 512 thr, 1024 records/block. Dense f4 staging (fully coalesced),
// stride-1 consume (bank-benign), in-LDS partition into 5 range segments,
// one global atomic per range per block, coalesced flush.
__global__ __launch_bounds__(512)
void decode_kernel(const float* __restrict__ p2, const float* __restrict__ p3,
                   const float* __restrict__ p4, const float* __restrict__ p5,
                   u32* __restrict__ counters, uint2* __restrict__ cand)
{
  __shared__ float4 sbuf4[1536];          // 24 KB  (1024 records)
  __shared__ uint2 stg[1024];             // 8 KB   partitioned survivors
  __shared__ u32 lcnt[8], lseg[8], lrank[8], gbase[8];
  const int tid = threadIdx.x;
  const int b = blockIdx.y;
  if (tid < 8) { lcnt[tid] = 0u; lrank[tid] = 0u; gbase[tid] = 0u; }

  const int rbase = blockIdx.x * 1024;
  const int FS = blockIdx.x * 1536;
  const float4* q2 = (const float4*)p2;
  const float4* q3 = (const float4*)p3;
  const float4* q4 = (const float4*)p4;
  const float4* q5 = (const float4*)p5;
  #pragma unroll
  for (int j = 0; j < 3; ++j) {
    int idx4 = FS + j * 512 + tid;
    if (idx4 < F4TOT) {
      const float4* src;
      if (idx4 < F4B3)      src = q2 + (size_t)b * 138624 + idx4;
      else if (idx4 < F4B4) src = q3 + (size_t)b * 34656  + (idx4 - F4B3);
      else if (idx4 < F4B5) src = q4 + (size_t)b * 8664   + (idx4 - F4B4);
      else                  src = q5 + (size_t)b * 2166   + (idx4 - F4B5);
      sbuf4[j * 512 + tid] = *src;
    }
  }
  __syncthreads();

  // score + classify (2 records/thread, stride-1 within each half)
  const float* sbuf = (const float*)sbuf4;
  u32 kb[2]; u32 kg[2]; int kr[2];
  #pragma unroll
  for (int k = 0; k < 2; ++k) {
    kb[k] = 0u; kr[k] = -1;
    int lr = tid + k * 512;
    int rg = rbase + lr;
    kg[k] = (u32)rg;
    if (rg < NTOT) {
      float2 cc = *(const float2*)&sbuf[lr * 6 + 4];
      float s = sigm(cc.x) * sigm(cc.y);
      if (s >= SCORE_T) {
        u32 bb = __float_as_uint(s);
        kb[k] = bb;
        int r;
        if      (bb >= RT0) r = 0;
        else if (bb >= RT1) r = 1;
        else if (bb >= RT2) r = 2;
        else if (bb >= RT3) r = 3;
        else                r = 4;
        kr[k] = r;
        atomicAdd(&lcnt[r], 1u);
      }
    }
  }
  __syncthreads();
  if (tid == 0) {
    u32 s = 0;
    #pragma unroll
    for (int r = 0; r < 5; ++r) { lseg[r] = s; s += lcnt[r]; }
  }
  if (tid < 5 && lcnt[tid]) gbase[tid] = atomicAdd(&counters[(size_t)b * CSTRIDE + tid * 16], lcnt[tid]);
  __syncthreads();
  #pragma unroll
  for (int k = 0; k < 2; ++k) {
    if (kr[k] >= 0) {
      u32 rk = atomicAdd(&lrank[kr[k]], 1u);
      stg[lseg[kr[k]] + rk] = make_uint2(kb[k], kg[k]);
    }
  }
  __syncthreads();
  // coalesced flush per range
  uint2* cb = cand + (size_t)b * BATCH_ENT;
  const u32 roff[5] = { OFF0, OFF1, OFF2, OFF3, OFF4 };
  const u32 rcap[5] = { CAP0, CAP1, CAP2, CAP3, CAP4 };
  #pragma unroll
  for (int r = 0; r < 5; ++r) {
    const u32 cnt = lcnt[r], sg = lseg[r], gb = gbase[r];
    for (u32 i = tid; i < cnt; i += 512) {
      u32 d = gb + i;
      if (d < rcap[r]) cb[roff[r] + d] = stg[sg + i];
    }
  }
}

// ---------------------------------------------------------------- M: range-pruned hist+scan+sort+NMS
// One block per batch. Reads the smallest prefix of ranges with cum count >= min(KTOP,total);
// the keep-set (bins >= cutoff) is provably inside that prefix. Overflowed-and-needed range
// -> exact full-rescan fallback (statistically never).
__global__ __launch_bounds__(1024, 1)
void mega_kernel(const u32* __restrict__ counters, const uint2* __restrict__ cand,
                 const float* __restrict__ p2, const float* __restrict__ p3,
                 const float* __restrict__ p4, const float* __restrict__ p5,
                 float* __restrict__ out)
{
  const int b = blockIdx.x;
  const int tid = threadIdx.x;

  __shared__ u32 sstart[NBIN];            // 16 KB
  __shared__ u32 scur[NBIN];              // 16 KB
  __shared__ u64 skey[KTOP];              // 8 KB
  __shared__ u64 skey2[KTOP];             // 8 KB
  __shared__ float4 sbox[WIN];            // 4 KB
  __shared__ u64 smat[WIN * 4];           // 8 KB
  __shared__ float4 selbox[100];          // 1.6 KB
  __shared__ int s_misc[4];
  __shared__ int s_B, s_n;

  const u32 c0 = counters[(size_t)b * CSTRIDE +  0];
  const u32 c1 = counters[(size_t)b * CSTRIDE + 16];
  const u32 c2 = counters[(size_t)b * CSTRIDE + 32];
  const u32 c3 = counters[(size_t)b * CSTRIDE + 48];
  const u32 c4 = counters[(size_t)b * CSTRIDE + 64];
  const u32 total = c0 + c1 + c2 + c3 + c4;
  const u32 need = min((u32)KTOP, total);
  int RL = 0;
  { u32 cum = c0;
    if (cum < need) { RL = 1; cum += c1; }
    if (cum < need) { RL = 2; cum += c2; }
    if (cum < need) { RL = 3; cum += c3; }
    if (cum < need) { RL = 4; cum += c4; }
  }
  const bool fb = (c0 > (u32)CAP0)
               || (RL >= 1 && c1 > (u32)CAP1)
               || (RL >= 2 && c2 > (u32)CAP2)
               || (RL >= 3 && c3 > (u32)CAP3)
               || (RL >= 4 && c4 > (u32)CAP4);

  for (int i = tid; i < NBIN; i += 1024) scur[i] = 0u;
  __syncthreads();

  const uint2* cb = cand + (size_t)b * BATCH_ENT;

  // ---- hist (read ranges 0..RL)
  if (!fb) {
    for (u32 i = tid; i < c0; i += 1024) atomicAdd(&scur[score_bin(cb[OFF0 + i].x)], 1u);
    if (RL >= 1) for (u32 i = tid; i < c1; i += 1024) atomicAdd(&scur[score_bin(cb[OFF1 + i].x)], 1u);
    if (RL >= 2) for (u32 i = tid; i < c2; i += 1024) atomicAdd(&scur[score_bin(cb[OFF2 + i].x)], 1u);
    if (RL >= 3) for (u32 i = tid; i < c3; i += 1024) atomicAdd(&scur[score_bin(cb[OFF3 + i].x)], 1u);
    if (RL >= 4) for (u32 i = tid; i < c4; i += 1024) atomicAdd(&scur[score_bin(cb[OFF4 + i].x)], 1u);
  } else {
    for (int P = tid; P < NPAIR; P += 1024) {
      u32 b0, b1, gi0, gi1;
      score_pair(P, b, p2, p3, p4, p5, b0, b1, gi0, gi1);
      if (b0) atomicAdd(&scur[score_bin(b0)], 1u);
      if (b1) atomicAdd(&scur[score_bin(b1)], 1u);
    }
  }
  __syncthreads();

  // ---- wave-0 shfl suffix scan + min-reduce cutoff
  if (tid < 64) {
    u32 h[64];
    #pragma unroll
    for (int k = 0; k < 64; ++k) h[k] = scur[tid * 64 + k];
    u32 lsum = 0;
    #pragma unroll
    for (int k = 0; k < 64; ++k) lsum += h[k];
    u32 S = lsum;
    #pragma unroll
    for (int off = 1; off < 64; off <<= 1) {
      u32 v = (u32)__shfl_down((int)S, off, 64);
      if (tid + off < 64) S += v;
    }
    u32 c = S - lsum;                           // cnt_ge(64*tid + 64)
    int Bv = -1; u32 nv = 0;
    for (int k = 63; k >= 0; --k) {
      sstart[tid * 64 + k] = c;                 // cnt_ge(bin+1)
      c += h[k];                                // cnt_ge(bin)
      if (c <= (u32)KTOP) { Bv = tid * 64 + k; nv = c; }
    }
    u32 pk = (Bv < 0) ? 0xFFFFFFFFu : (((u32)Bv << 12) | nv);
    #pragma unroll
    for (int off = 32; off >= 1; off >>= 1) {
      u32 o = (u32)__shfl_down((int)pk, off, 64);
      if (tid + off < 64) pk = min(pk, o);
    }
    if (tid == 0) {
      if (pk == 0xFFFFFFFFu) { s_B = 4095; s_n = KTOP; }
      else { s_B = max((int)(pk >> 12), 1); s_n = (int)(pk & 0xFFFu); }
    }
  }
  __syncthreads();
  const int B = s_B;
  const int n = min(s_n, KTOP);

  for (int i = tid; i < NBIN; i += 1024) scur[i] = sstart[i];
  __syncthreads();

  // ---- scatter survivors (bin >= B) into counting slots
  if (!fb) {
    for (u32 i = tid; i < c0; i += 1024) {
      uint2 e = cb[OFF0 + i]; int bin = score_bin(e.x);
      if (bin >= B) { u32 sl = atomicAdd(&scur[bin], 1u);
        if (sl < (u32)KTOP) skey[sl] = ((u64)e.x << 32) | (u32)(~e.y); }
    }
    if (RL >= 1) for (u32 i = tid; i < c1; i += 1024) {
      uint2 e = cb[OFF1 + i]; int bin = score_bin(e.x);
      if (bin >= B) { u32 sl = atomicAdd(&scur[bin], 1u);
        if (sl < (u32)KTOP) skey[sl] = ((u64)e.x << 32) | (u32)(~e.y); }
    }
    if (RL >= 2) for (u32 i = tid; i < c2; i += 1024) {
      uint2 e = cb[OFF2 + i]; int bin = score_bin(e.x);
      if (bin >= B) { u32 sl = atomicAdd(&scur[bin], 1u);
        if (sl < (u32)KTOP) skey[sl] = ((u64)e.x << 32) | (u32)(~e.y); }
    }
    if (RL >= 3) for (u32 i = tid; i < c3; i += 1024) {
      uint2 e = cb[OFF3 + i]; int bin = score_bin(e.x);
      if (bin >= B) { u32 sl = atomicAdd(&scur[bin], 1u);
        if (sl < (u32)KTOP) skey[sl] = ((u64)e.x << 32) | (u32)(~e.y); }
    }
    if (RL >= 4) for (u32 i = tid; i < c4; i += 1024) {
      uint2 e = cb[OFF4 + i]; int bin = score_bin(e.x);
      if (bin >= B) { u32 sl = atomicAdd(&scur[bin], 1u);
        if (sl < (u32)KTOP) skey[sl] = ((u64)e.x << 32) | (u32)(~e.y); }
    }
  } else {
    for (int P = tid; P < NPAIR; P += 1024) {
      u32 b0, b1, gi0, gi1;
      score_pair(P, b, p2, p3, p4, p5, b0, b1, gi0, gi1);
      if (b0) { int bin = score_bin(b0);
        if (bin >= B) { u32 sl = atomicAdd(&scur[bin], 1u);
          if (sl < (u32)KTOP) skey[sl] = ((u64)b0 << 32) | (u32)(~gi0); } }
      if (b1) { int bin = score_bin(b1);
        if (bin >= B) { u32 sl = atomicAdd(&scur[bin], 1u);
          if (sl < (u32)KTOP) skey[sl] = ((u64)b1 << 32) | (u32)(~gi1); } }
    }
  }
  __syncthreads();

  // ---- exact rank sort within bins (barrier-free)
  for (int s = tid; s < n; s += 1024) {
    u64 k = skey[s];
    int bin = score_bin((u32)(k >> 32));
    int st = (int)sstart[bin];
    int en = (int)scur[bin];
    u32 r = 0;
    for (int j = st; j < en; ++j) r += (skey[j] > k) ? 1u : 0u;
    skey2[st + r] = k;
  }
  __syncthreads();

  const int Wn = min(n, WIN);

  // ---- window boxes
  if (tid < WIN) {
    sbox[tid] = (tid < Wn) ? decode_box_from_gidx(~(u32)skey2[tid], b, p2, p3, p4, p5)
                           : make_float4(0.f, 0.f, 0.f, 0.f);
  }
  __syncthreads();

  // ---- IoU bitmask matrix; row = tid&255, word = tid>>8 (broadcast reads)
  {
    int row = tid & 255, word = tid >> 8;
    u64 bits = 0;
    if (row < Wn) {
      float4 A = sbox[row];
      int j0 = word * 64;
      int je = min(64, Wn - j0);
      for (int j = 0; j < je; ++j)
        if (iou_gt(A, sbox[j0 + j])) bits |= (1ull << j);
    }
    smat[word * 256 + row] = bits;
  }
  __syncthreads();

  // ---- greedy selection on wave 0, matrix rows in registers
  if (tid < 64) {
    const int lane = tid;
    u64 m0[4], m1[4], m2[4], m3[4];
    #pragma unroll
    for (int w = 0; w < 4; ++w) {
      m0[w] = smat[w * 256 +   0 + lane];
      m1[w] = smat[w * 256 +  64 + lane];
      m2[w] = smat[w * 256 + 128 + lane];
      m3[w] = smat[w * 256 + 192 + lane];
    }
    u64 live[4];
    #pragma unroll
    for (int g2 = 0; g2 < 4; ++g2) {
      int lo = g2 * 64;
      live[g2] = (Wn >= lo + 64) ? ~0ull : (Wn > lo ? ((1ull << (Wn - lo)) - 1ull) : 0ull);
    }
    int sel = 0;
    #pragma unroll 1
    for (int w2 = 0; w2 < 4; ++w2) {
      while (live[w2] && sel < 100) {
        int j = (int)__ffsll(live[w2]) - 1;
        int p = (w2 << 6) + j;
        u64 r0, r1, r2, r3;
        if (w2 == 0)      { r0 = shfl_u64(m0[0], j); r1 = shfl_u64(m0[1], j); r2 = shfl_u64(m0[2], j); r3 = shfl_u64(m0[3], j); }
        else if (w2 == 1) { r0 = shfl_u64(m1[0], j); r1 = shfl_u64(m1[1], j); r2 = shfl_u64(m1[2], j); r3 = shfl_u64(m1[3], j); }
        else if (w2 == 2) { r0 = shfl_u64(m2[0], j); r1 = shfl_u64(m2[1], j); r2 = shfl_u64(m2[2], j); r3 = shfl_u64(m2[3], j); }
        else              { r0 = shfl_u64(m3[0], j); r1 = shfl_u64(m3[1], j); r2 = shfl_u64(m3[2], j); r3 = shfl_u64(m3[3], j); }
        live[0] &= ~r0; live[1] &= ~r1; live[2] &= ~r2; live[3] &= ~r3;
        live[w2] &= ~(1ull << j);
        if (lane == 0) {
          float4 box = sbox[p];
          u64 k = skey2[p];
          float sc = __uint_as_float((u32)(k >> 32));
          selbox[sel] = box;
          float* orow = out + (size_t)b * 500 + (size_t)sel * 5;
          orow[0] = box.x; orow[1] = box.y; orow[2] = box.z; orow[3] = box.w; orow[4] = sc;
        }
        sel++;
      }
    }
    if (lane == 0) {
      s_misc[2] = sel;
      s_misc[3] = (sel < 100 && n > WIN) ? 1 : 0;
    }
  }
  __syncthreads();

  // ---- exact slow path beyond the window (statistically never taken)
  if (s_misc[3]) {
    if (tid < 64) {
      const int lane = tid;
      int sel = s_misc[2];
      for (int p = WIN; p < n && sel < 100; ++p) {
        u64 k = skey2[p];
        float4 box = decode_box_from_gidx(~(u32)k, b, p2, p3, p4, p5);
        bool hit = false;
        if (lane < sel) hit = iou_gt(selbox[lane], box);
        if (lane + 64 < sel) hit = hit || iou_gt(selbox[lane + 64], box);
        u64 anyhit = __ballot(hit);
        if (anyhit == 0ull) {
          if (lane == 0) {
            selbox[sel] = box;
            float sc = __uint_as_float((u32)(k >> 32));
            float* orow = out + (size_t)b * 500 + (size_t)sel * 5;
            orow[0] = box.x; orow[1] = box.y; orow[2] = box.z; orow[3] = box.w; orow[4] = sc;
          }
          sel++;
        }
      }
      if (lane == 0) s_misc[2] = sel;
    }
  }
  __syncthreads();

  // ---- zero-fill remaining rows
  const int nsel = s_misc[2];
  for (int i = tid; i < (100 - nsel) * 5; i += 1024)
    out[(size_t)b * 500 + (size_t)nsel * 5 + i] = 0.0f;
}

// ---------------------------------------------------------------- launch
extern "C" void kernel_launch(void* const* d_in, const int* in_sizes, int n_in,
                              void* d_out, int out_size, void* d_ws, size_t ws_size,
                              hipStream_t stream) {
  const float* p2 = (const float*)d_in[0];
  const float* p3 = (const float*)d_in[1];
  const float* p4 = (const float*)d_in[2];
  const float* p5 = (const float*)d_in[3];
  float* out = (float*)d_out;

  unsigned char* w = (unsigned char*)d_ws;
  u32*   counters = (u32*)w;
  uint2* cand     = (uint2*)(w + WS_CAND);

  hipMemsetAsync(counters, 0, 32 * CSTRIDE * sizeof(u32), stream);
  decode_kernel<<<dim3(120, 32), 512, 0, stream>>>(p2, p3, p4, p5, counters, cand);
  mega_kernel<<<32, 1024, 0, stream>>>(counters, cand, p2, p3, p4, p5, out);
}